// Round 1
// baseline (1970.388 us; speedup 1.0000x reference)
//
#include <hip/hip_runtime.h>
#include <math.h>

constexpr int NN  = 50000;   // nodes
constexpr int NE  = 150000;  // edges
constexpr int NIN = 16;      // node features in
constexpr int EIN = 19;      // edge features in
constexpr int HD  = 32;      // hidden H

#define LEAK  0.1f
#define BNEPS 1e-5f

__device__ __forceinline__ float lky(float v){ return fmaxf(v, LEAK*v); }

// ---------------------------------------------------------------- zero
__global__ void zero_kernel(float* __restrict__ p, int n){
  int stride = gridDim.x * blockDim.x;
  for(int i = blockIdx.x*blockDim.x + threadIdx.x; i < n; i += stride) p[i] = 0.f;
}

// ---------------------------------------------------------------- BN stats (sum, sumsq per column)
template<int C>
__global__ void stats_kernel(const float* __restrict__ data, int rows, float* __restrict__ sums){
  __shared__ float ls[2*C];
  for(int i = threadIdx.x; i < 2*C; i += blockDim.x) ls[i] = 0.f;
  __syncthreads();
  float s[C], q[C];
  #pragma unroll
  for(int c = 0; c < C; c++){ s[c] = 0.f; q[c] = 0.f; }
  int stride = gridDim.x * blockDim.x;
  for(int r = blockIdx.x*blockDim.x + threadIdx.x; r < rows; r += stride){
    const float* rp = data + (size_t)r * C;
    #pragma unroll
    for(int c = 0; c < C; c++){ float v = rp[c]; s[c] += v; q[c] += v*v; }
  }
  #pragma unroll
  for(int c = 0; c < C; c++){ atomicAdd(&ls[c], s[c]); atomicAdd(&ls[C+c], q[c]); }
  __syncthreads();
  for(int i = threadIdx.x; i < 2*C; i += blockDim.x) atomicAdd(&sums[i], ls[i]);
}

// ss layout: scale_e[19], shift_e[19], scale_x[16], shift_x[16]
__global__ void finalize_stats(const float* __restrict__ sums_e, const float* __restrict__ sums_x,
                               const float* __restrict__ ge, const float* __restrict__ be,
                               const float* __restrict__ gx, const float* __restrict__ bx,
                               float* __restrict__ ss){
  int t = threadIdx.x;
  if(t < EIN){
    float m = sums_e[t] / (float)NE;
    float v = sums_e[EIN+t] / (float)NE - m*m;
    float sc = ge[t] * rsqrtf(v + BNEPS);
    ss[t] = sc; ss[EIN+t] = be[t] - m*sc;
  } else if(t < EIN + NIN){
    int c = t - EIN;
    float m = sums_x[c] / (float)NN;
    float v = sums_x[NIN+c] / (float)NN - m*m;
    float sc = gx[c] * rsqrtf(v + BNEPS);
    ss[2*EIN + c] = sc; ss[2*EIN + NIN + c] = bx[c] - m*sc;
  }
}

template<int C>
__global__ void normalize_kernel(const float* __restrict__ in, float* __restrict__ outp,
                                 const float* __restrict__ ss, int rows){
  int n = rows * C;
  int stride = gridDim.x * blockDim.x;
  for(int i = blockIdx.x*blockDim.x + threadIdx.x; i < n; i += stride){
    int c = i % C;
    outp[i] = in[i] * ss[c] + ss[C + c];
  }
}

// ---------------------------------------------------------------- x_next = x @ root + bias
template<int DIN>
__global__ __launch_bounds__(256) void root_kernel(const float* __restrict__ xin,
                                                   const float* __restrict__ root,
                                                   const float* __restrict__ bias,
                                                   float* __restrict__ xout){
  int idx = blockIdx.x*blockDim.x + threadIdx.x;
  if(idx >= NN * HD) return;
  int node = idx / HD, o = idx % HD;
  const float* xr = xin + (size_t)node * DIN;
  float acc = bias[o];
  #pragma unroll
  for(int k = 0; k < DIN; k++) acc += xr[k] * root[k*HD + o];
  xout[idx] = acc;
}

// ---------------------------------------------------------------- fused NNConv message + scatter
// per edge: t1 = leaky(e_bn @ W1 + b1); msg[o] = sum_i x[row][i]*leaky((t1@W2)[i*H+o]+b2[i*H+o])
// atomicAdd into xout[col]
template<int DIN>
__global__ __launch_bounds__(256) void msg_kernel(const float* __restrict__ ebn,
                                                  const int* __restrict__ row,
                                                  const int* __restrict__ col,
                                                  const float* __restrict__ xin,
                                                  const float* __restrict__ W1,
                                                  const float* __restrict__ b1,
                                                  const float* __restrict__ W2,
                                                  const float* __restrict__ b2,
                                                  float* __restrict__ xout){
  int e = blockIdx.x*blockDim.x + threadIdx.x;
  if(e >= NE) return;
  int r = row[e], c = col[e];

  float eb[EIN];
  const float* ep = ebn + (size_t)e * EIN;
  #pragma unroll
  for(int j = 0; j < EIN; j++) eb[j] = ep[j];

  float t1[DIN];
  #pragma unroll
  for(int j = 0; j < DIN; j++){
    float a = b1[j];
    #pragma unroll
    for(int k = 0; k < EIN; k++) a += eb[k] * W1[k*DIN + j];
    t1[j] = lky(a);
  }

  const float* xr = xin + (size_t)r * DIN;
  float msg[HD];
  #pragma unroll
  for(int o = 0; o < HD; o++) msg[o] = 0.f;

  #pragma unroll 1
  for(int i = 0; i < DIN; i++){
    float w[HD];
    const float* b2p = b2 + i*HD;
    #pragma unroll
    for(int o = 0; o < HD; o++) w[o] = b2p[o];
    #pragma unroll
    for(int k = 0; k < DIN; k++){
      float t = t1[k];
      const float* w2p = W2 + (size_t)k*(DIN*HD) + i*HD;   // uniform -> s_load
      #pragma unroll
      for(int o = 0; o < HD; o++) w[o] += t * w2p[o];
    }
    float xi = xr[i];
    #pragma unroll
    for(int o = 0; o < HD; o++) msg[o] += xi * lky(w[o]);
  }

  float* outp = xout + (size_t)c * HD;
  #pragma unroll
  for(int o = 0; o < HD; o++) atomicAdd(&outp[o], msg[o]);
}

// ---------------------------------------------------------------- fused MetaLayer edge model
__global__ __launch_bounds__(256) void pred_edge_kernel(const float* __restrict__ x,
                                                        const float* __restrict__ ebn,
                                                        const int* __restrict__ row,
                                                        const int* __restrict__ col,
                                                        const float* __restrict__ emW1,
                                                        const float* __restrict__ emb1,
                                                        const float* __restrict__ emW2,
                                                        const float* __restrict__ emb2,
                                                        const float* __restrict__ nm1W1,
                                                        const float* __restrict__ nm1b1,
                                                        const float* __restrict__ nm1W2,
                                                        const float* __restrict__ nm1b2,
                                                        float* __restrict__ agg,
                                                        float* __restrict__ cnt){
  int e = blockIdx.x*blockDim.x + threadIdx.x;
  if(e >= NE) return;
  int r = row[e], c = col[e];

  float xr[HD], xc[HD], eb[EIN];
  #pragma unroll
  for(int k = 0; k < HD; k++) xr[k] = x[(size_t)r*HD + k];
  #pragma unroll
  for(int k = 0; k < HD; k++) xc[k] = x[(size_t)c*HD + k];
  #pragma unroll
  for(int k = 0; k < EIN; k++) eb[k] = ebn[(size_t)e*EIN + k];

  // u = leaky([xr, xc, eb] @ emW1 + emb1)
  float u[HD];
  #pragma unroll
  for(int o = 0; o < HD; o++) u[o] = emb1[o];
  #pragma unroll
  for(int k = 0; k < HD; k++){ float v = xr[k]; const float* wp = emW1 + k*HD;
    #pragma unroll
    for(int o = 0; o < HD; o++) u[o] += v * wp[o]; }
  #pragma unroll
  for(int k = 0; k < HD; k++){ float v = xc[k]; const float* wp = emW1 + (HD+k)*HD;
    #pragma unroll
    for(int o = 0; o < HD; o++) u[o] += v * wp[o]; }
  #pragma unroll
  for(int k = 0; k < EIN; k++){ float v = eb[k]; const float* wp = emW1 + (2*HD+k)*HD;
    #pragma unroll
    for(int o = 0; o < HD; o++) u[o] += v * wp[o]; }
  #pragma unroll
  for(int o = 0; o < HD; o++) u[o] = lky(u[o]);

  // e2 = u @ emW2 + emb2
  float e2[HD];
  #pragma unroll
  for(int o = 0; o < HD; o++) e2[o] = emb2[o];
  #pragma unroll
  for(int k = 0; k < HD; k++){ float v = u[k]; const float* wp = emW2 + k*HD;
    #pragma unroll
    for(int o = 0; o < HD; o++) e2[o] += v * wp[o]; }

  // v = leaky([xr, e2] @ nm1W1 + nm1b1)
  float vv[HD];
  #pragma unroll
  for(int o = 0; o < HD; o++) vv[o] = nm1b1[o];
  #pragma unroll
  for(int k = 0; k < HD; k++){ float v = xr[k]; const float* wp = nm1W1 + k*HD;
    #pragma unroll
    for(int o = 0; o < HD; o++) vv[o] += v * wp[o]; }
  #pragma unroll
  for(int k = 0; k < HD; k++){ float v = e2[k]; const float* wp = nm1W1 + (HD+k)*HD;
    #pragma unroll
    for(int o = 0; o < HD; o++) vv[o] += v * wp[o]; }
  #pragma unroll
  for(int o = 0; o < HD; o++) vv[o] = lky(vv[o]);

  // h = vv @ nm1W2 + nm1b2 ; scatter
  float* aggp = agg + (size_t)c * HD;
  #pragma unroll
  for(int o = 0; o < HD; o++){
    float h = nm1b2[o];
    #pragma unroll
    for(int k = 0; k < HD; k++) h += vv[k] * nm1W2[k*HD + o];
    atomicAdd(&aggp[o], h);
  }
  atomicAdd(&cnt[c], 1.f);
}

// ---------------------------------------------------------------- final node model + log_softmax
__global__ __launch_bounds__(256) void final_kernel(const float* __restrict__ x,
                                                    const float* __restrict__ agg,
                                                    const float* __restrict__ cnt,
                                                    const float* __restrict__ W1,
                                                    const float* __restrict__ b1,
                                                    const float* __restrict__ W2,
                                                    const float* __restrict__ b2,
                                                    float* __restrict__ out){
  int n = blockIdx.x*blockDim.x + threadIdx.x;
  if(n >= NN) return;
  float inv = 1.f / fmaxf(cnt[n], 1.f);
  const float* xp = x + (size_t)n * HD;
  const float* ap = agg + (size_t)n * HD;

  float t[HD];
  #pragma unroll
  for(int o = 0; o < HD; o++) t[o] = b1[o];
  #pragma unroll
  for(int k = 0; k < HD; k++){ float v = xp[k]; const float* wp = W1 + k*HD;
    #pragma unroll
    for(int o = 0; o < HD; o++) t[o] += v * wp[o]; }
  #pragma unroll
  for(int k = 0; k < HD; k++){ float v = ap[k] * inv; const float* wp = W1 + (HD+k)*HD;
    #pragma unroll
    for(int o = 0; o < HD; o++) t[o] += v * wp[o]; }

  float a0 = b2[0], a1 = b2[1];
  #pragma unroll
  for(int k = 0; k < HD; k++){ float v = lky(t[k]); a0 += v * W2[k*2]; a1 += v * W2[k*2+1]; }

  float m  = fmaxf(a0, a1);
  float ls = m + logf(expf(a0 - m) + expf(a1 - m));
  out[(size_t)n*2]   = a0 - ls;
  out[(size_t)n*2+1] = a1 - ls;
}

// ---------------------------------------------------------------- launch
extern "C" void kernel_launch(void* const* d_in, const int* in_sizes, int n_in,
                              void* d_out, int out_size, void* d_ws, size_t ws_size,
                              hipStream_t stream){
  const float* x  = (const float*)d_in[0];
  const int*   ei = (const int*)  d_in[1];
  const float* e  = (const float*)d_in[2];
  const float* bn_node_g = (const float*)d_in[4];
  const float* bn_node_b = (const float*)d_in[5];
  const float* bn_edge_g = (const float*)d_in[6];
  const float* bn_edge_b = (const float*)d_in[7];
  // layer params: 8 + 6*l
  const float* lW1[3], *lb1[3], *lW2[3], *lb2[3], *lroot[3], *lbias[3];
  for(int l = 0; l < 3; l++){
    lW1[l]   = (const float*)d_in[8 + 6*l + 0];
    lb1[l]   = (const float*)d_in[8 + 6*l + 1];
    lW2[l]   = (const float*)d_in[8 + 6*l + 2];
    lb2[l]   = (const float*)d_in[8 + 6*l + 3];
    lroot[l] = (const float*)d_in[8 + 6*l + 4];
    lbias[l] = (const float*)d_in[8 + 6*l + 5];
  }
  const float* emW1  = (const float*)d_in[26];
  const float* emb1  = (const float*)d_in[27];
  const float* emW2  = (const float*)d_in[28];
  const float* emb2  = (const float*)d_in[29];
  const float* nm1W1 = (const float*)d_in[30];
  const float* nm1b1 = (const float*)d_in[31];
  const float* nm1W2 = (const float*)d_in[32];
  const float* nm1b2 = (const float*)d_in[33];
  const float* nm2W1 = (const float*)d_in[34];
  const float* nm2b1 = (const float*)d_in[35];
  const float* nm2W2 = (const float*)d_in[36];
  const float* nm2b2 = (const float*)d_in[37];

  const int* rowp = ei;
  const int* colp = ei + NE;

  float* ws   = (float*)d_ws;
  float* e_bn = ws;                               // NE*EIN
  float* x_bn = e_bn + (size_t)NE*EIN;            // NN*NIN
  float* x_a  = x_bn + (size_t)NN*NIN;            // NN*HD
  float* x_b  = x_a  + (size_t)NN*HD;             // NN*HD
  float* agg  = x_b  + (size_t)NN*HD;             // NN*HD
  float* cnt  = agg  + (size_t)NN*HD;             // NN
  float* stats= cnt  + NN;                        // 256 floats
  float* sums_e = stats;        // 38 used
  float* sums_x = stats + 64;   // 32 used
  float* ss     = stats + 128;  // 70 used

  // zero agg + cnt + stats (contiguous)
  zero_kernel<<<2048, 256, 0, stream>>>(agg, NN*HD + NN + 256);

  stats_kernel<EIN><<<256, 256, 0, stream>>>(e, NE, sums_e);
  stats_kernel<NIN><<<256, 256, 0, stream>>>(x, NN, sums_x);
  finalize_stats<<<1, 64, 0, stream>>>(sums_e, sums_x, bn_edge_g, bn_edge_b,
                                       bn_node_g, bn_node_b, ss);
  normalize_kernel<EIN><<<2048, 256, 0, stream>>>(e, e_bn, ss, NE);
  normalize_kernel<NIN><<<1024, 256, 0, stream>>>(x, x_bn, ss + 2*EIN, NN);

  int eblocks = (NE + 255) / 256;
  int nblocks = (NN*HD + 255) / 256;

  // layer 0: x_bn (din=16) -> x_a
  root_kernel<NIN><<<nblocks, 256, 0, stream>>>(x_bn, lroot[0], lbias[0], x_a);
  msg_kernel<NIN><<<eblocks, 256, 0, stream>>>(e_bn, rowp, colp, x_bn,
                                               lW1[0], lb1[0], lW2[0], lb2[0], x_a);
  // layer 1: x_a (din=32) -> x_b
  root_kernel<HD><<<nblocks, 256, 0, stream>>>(x_a, lroot[1], lbias[1], x_b);
  msg_kernel<HD><<<eblocks, 256, 0, stream>>>(e_bn, rowp, colp, x_a,
                                              lW1[1], lb1[1], lW2[1], lb2[1], x_b);
  // layer 2: x_b (din=32) -> x_a
  root_kernel<HD><<<nblocks, 256, 0, stream>>>(x_b, lroot[2], lbias[2], x_a);
  msg_kernel<HD><<<eblocks, 256, 0, stream>>>(e_bn, rowp, colp, x_b,
                                              lW1[2], lb1[2], lW2[2], lb2[2], x_a);

  // predictor
  pred_edge_kernel<<<eblocks, 256, 0, stream>>>(x_a, e_bn, rowp, colp,
                                                emW1, emb1, emW2, emb2,
                                                nm1W1, nm1b1, nm1W2, nm1b2,
                                                agg, cnt);
  final_kernel<<<(NN + 255)/256, 256, 0, stream>>>(x_a, agg, cnt,
                                                   nm2W1, nm2b1, nm2W2, nm2b2,
                                                   (float*)d_out);
}

// Round 2
// 1159.391 us; speedup vs baseline: 1.6995x; 1.6995x over previous
//
#include <hip/hip_runtime.h>
#include <math.h>

constexpr int NN  = 50000;   // nodes
constexpr int NE  = 150000;  // edges
constexpr int NIN = 16;      // node features in
constexpr int EIN = 19;      // edge features in
constexpr int HD  = 32;      // hidden H

#define LEAK  0.1f
#define BNEPS 1e-5f

__device__ __forceinline__ float lky(float v){ return fmaxf(v, LEAK*v); }

// ---------------------------------------------------------------- zero
__global__ void zero_kernel(float* __restrict__ p, int n){
  int stride = gridDim.x * blockDim.x;
  for(int i = blockIdx.x*blockDim.x + threadIdx.x; i < n; i += stride) p[i] = 0.f;
}

// ---------------------------------------------------------------- BN stats (sum, sumsq per column)
template<int C>
__global__ void stats_kernel(const float* __restrict__ data, int rows, float* __restrict__ sums){
  __shared__ float ls[2*C];
  for(int i = threadIdx.x; i < 2*C; i += blockDim.x) ls[i] = 0.f;
  __syncthreads();
  float s[C], q[C];
  #pragma unroll
  for(int c = 0; c < C; c++){ s[c] = 0.f; q[c] = 0.f; }
  int stride = gridDim.x * blockDim.x;
  for(int r = blockIdx.x*blockDim.x + threadIdx.x; r < rows; r += stride){
    const float* rp = data + (size_t)r * C;
    #pragma unroll
    for(int c = 0; c < C; c++){ float v = rp[c]; s[c] += v; q[c] += v*v; }
  }
  #pragma unroll
  for(int c = 0; c < C; c++){ atomicAdd(&ls[c], s[c]); atomicAdd(&ls[C+c], q[c]); }
  __syncthreads();
  for(int i = threadIdx.x; i < 2*C; i += blockDim.x) atomicAdd(&sums[i], ls[i]);
}

// ss layout: scale_e[19], shift_e[19], scale_x[16], shift_x[16]
__global__ void finalize_stats(const float* __restrict__ sums_e, const float* __restrict__ sums_x,
                               const float* __restrict__ ge, const float* __restrict__ be,
                               const float* __restrict__ gx, const float* __restrict__ bx,
                               float* __restrict__ ss){
  int t = threadIdx.x;
  if(t < EIN){
    float m = sums_e[t] / (float)NE;
    float v = sums_e[EIN+t] / (float)NE - m*m;
    float sc = ge[t] * rsqrtf(v + BNEPS);
    ss[t] = sc; ss[EIN+t] = be[t] - m*sc;
  } else if(t < EIN + NIN){
    int c = t - EIN;
    float m = sums_x[c] / (float)NN;
    float v = sums_x[NIN+c] / (float)NN - m*m;
    float sc = gx[c] * rsqrtf(v + BNEPS);
    ss[2*EIN + c] = sc; ss[2*EIN + NIN + c] = bx[c] - m*sc;
  }
}

// ---------------------------------------------------------------- fold BN(e) into W1/b1 of each layer + predictor edge rows
// W1f[l][k*DIN+j] = ss_e[k]*W1[k*DIN+j];  b1f[l][j] = b1[j] + sum_k sh_e[k]*W1[k*DIN+j]
__global__ void fold_kernel(const float* __restrict__ ss,
                            const float* __restrict__ l0W1, const float* __restrict__ l0b1,
                            const float* __restrict__ l1W1, const float* __restrict__ l1b1,
                            const float* __restrict__ l2W1, const float* __restrict__ l2b1,
                            const float* __restrict__ emW1, const float* __restrict__ emb1,
                            float* __restrict__ W1f, float* __restrict__ b1f,
                            float* __restrict__ emW1f, float* __restrict__ emb1f){
  int t = threadIdx.x;
  int seg = t >> 5, j = t & 31;
  if(seg == 0){
    if(j < NIN){
      float acc = l0b1[j];
      for(int k = 0; k < EIN; k++){
        W1f[0*640 + k*NIN + j] = ss[k] * l0W1[k*NIN + j];
        acc += ss[EIN+k] * l0W1[k*NIN + j];
      }
      b1f[0*32 + j] = acc;
    }
  } else if(seg == 1){
    float acc = l1b1[j];
    for(int k = 0; k < EIN; k++){
      W1f[1*640 + k*HD + j] = ss[k] * l1W1[k*HD + j];
      acc += ss[EIN+k] * l1W1[k*HD + j];
    }
    b1f[1*32 + j] = acc;
  } else if(seg == 2){
    float acc = l2b1[j];
    for(int k = 0; k < EIN; k++){
      W1f[2*640 + k*HD + j] = ss[k] * l2W1[k*HD + j];
      acc += ss[EIN+k] * l2W1[k*HD + j];
    }
    b1f[2*32 + j] = acc;
  } else if(seg == 3){
    float acc = emb1[j];
    for(int k = 0; k < EIN; k++){
      emW1f[k*HD + j] = ss[k] * emW1[(2*HD+k)*HD + j];
      acc += ss[EIN+k] * emW1[(2*HD+k)*HD + j];
    }
    emb1f[j] = acc;
  }
}

template<int C>
__global__ void normalize_kernel(const float* __restrict__ in, float* __restrict__ outp,
                                 const float* __restrict__ ss, int rows){
  int n = rows * C;
  int stride = gridDim.x * blockDim.x;
  for(int i = blockIdx.x*blockDim.x + threadIdx.x; i < n; i += stride){
    int c = i % C;
    outp[i] = in[i] * ss[c] + ss[C + c];
  }
}

// ---------------------------------------------------------------- T1 = leaky(e_raw @ W1f + b1f)   [E, DIN]
template<int DIN>
__global__ __launch_bounds__(256) void t1_kernel(const float* __restrict__ eraw,
                                                 const float* __restrict__ W1f,
                                                 const float* __restrict__ b1f,
                                                 float* __restrict__ T1){
  int idx = blockIdx.x*blockDim.x + threadIdx.x;
  if(idx >= NE*DIN) return;
  int e = idx / DIN, j = idx % DIN;
  const float* ep = eraw + (size_t)e*EIN;
  float a = b1f[j];
  #pragma unroll
  for(int k = 0; k < EIN; k++) a = fmaf(ep[k], W1f[k*DIN + j], a);
  T1[idx] = fmaxf(a, LEAK*a);
}

// ---------------------------------------------------------------- x_next = x @ root + bias
template<int DIN>
__global__ __launch_bounds__(256) void root_kernel(const float* __restrict__ xin,
                                                   const float* __restrict__ root,
                                                   const float* __restrict__ bias,
                                                   float* __restrict__ xout){
  int idx = blockIdx.x*blockDim.x + threadIdx.x;
  if(idx >= NN * HD) return;
  int node = idx / HD, o = idx % HD;
  const float* xr = xin + (size_t)node * DIN;
  float acc = bias[o];
  #pragma unroll
  for(int k = 0; k < DIN; k++) acc += xr[k] * root[k*HD + o];
  xout[idx] = acc;
}

// ---------------------------------------------------------------- msg v2: W2 in VGPRs, t1 in SGPRs
// 4 waves per block; wave w owns i in [w*IPW, (w+1)*IPW); lane (i2,o): i = w*IPW + i2*IPL + jj.
// Per edge (scalar loop): w(i,o) = b2[i,o] + sum_k t1[k]*W2[k][i*32+o]; msg[o] += x[row][i]*leaky(w).
// Reduce i2-halves by shfl, waves by LDS atomic, then one global atomic per (edge,o).
template<int DIN, int IPW, int EPB>
__global__ __launch_bounds__(256) void msg2_kernel(const float* __restrict__ T1,
                                                   const int* __restrict__ rowp,
                                                   const int* __restrict__ colp,
                                                   const float* __restrict__ xin,
                                                   const float* __restrict__ W2,
                                                   const float* __restrict__ b2,
                                                   float* __restrict__ xout){
  constexpr int IPL = IPW/2;
  const int lane = threadIdx.x & 63;
  const int i2 = lane >> 5, o = lane & 31;
  const int wid = __builtin_amdgcn_readfirstlane(threadIdx.x >> 6);
  const int i_base = wid*IPW + i2*IPL;

  // W2 slice + b2 slice resident in registers
  float w2r[IPL][DIN];
  #pragma unroll
  for(int jj = 0; jj < IPL; jj++)
    #pragma unroll
    for(int k = 0; k < DIN; k++)
      w2r[jj][k] = W2[k*(DIN*HD) + (i_base+jj)*HD + o];
  float b2r[IPL];
  #pragma unroll
  for(int jj = 0; jj < IPL; jj++) b2r[jj] = b2[(i_base+jj)*HD + o];

  __shared__ float msg_lds[EPB][HD];
  for(int t = threadIdx.x; t < EPB*HD; t += 256) ((float*)msg_lds)[t] = 0.f;
  __syncthreads();

  const int eb = blockIdx.x * EPB;
  const int nE = min(EPB, NE - eb);

  for(int s = 0; s < nE; ++s){
    const int e = eb + s;                       // scalar (uniform)
    const float* tp = T1 + (size_t)e * DIN;     // uniform base -> s_load
    float st1[DIN];
    #pragma unroll
    for(int k = 0; k < DIN; k++) st1[k] = tp[k];
    const int r = rowp[e];                      // uniform -> s_load
    const float* xp = xin + (size_t)r*DIN + wid*IPW + i2*IPL;
    float xv[IPL];
    #pragma unroll
    for(int jj = 0; jj < IPL; jj++) xv[jj] = xp[jj];

    float msgp = 0.f;
    #pragma unroll
    for(int jj = 0; jj < IPL; jj++){
      float w = b2r[jj];
      #pragma unroll
      for(int k = 0; k < DIN; k++) w = fmaf(st1[k], w2r[jj][k], w);
      float lw = fmaxf(w, LEAK*w);
      msgp = fmaf(xv[jj], lw, msgp);
    }
    msgp += __shfl_xor(msgp, 32);               // reduce i2 halves
    if(lane < 32) atomicAdd(&msg_lds[s][o], msgp);  // reduce waves (ds_add_f32)
  }
  __syncthreads();

  for(int t = threadIdx.x; t < nE*HD; t += 256){
    int s = t >> 5, oo = t & 31;
    int c = colp[eb + s];
    atomicAdd(&xout[(size_t)c*HD + oo], msg_lds[s][oo]);
  }
}

// ---------------------------------------------------------------- fused MetaLayer edge model (raw e, BN folded)
__global__ __launch_bounds__(256) void pred_edge_kernel(const float* __restrict__ x,
                                                        const float* __restrict__ eraw,
                                                        const int* __restrict__ row,
                                                        const int* __restrict__ col,
                                                        const float* __restrict__ emW1,
                                                        const float* __restrict__ emW1f,
                                                        const float* __restrict__ emb1f,
                                                        const float* __restrict__ emW2,
                                                        const float* __restrict__ emb2,
                                                        const float* __restrict__ nm1W1,
                                                        const float* __restrict__ nm1b1,
                                                        const float* __restrict__ nm1W2,
                                                        const float* __restrict__ nm1b2,
                                                        float* __restrict__ agg,
                                                        float* __restrict__ cnt){
  int e = blockIdx.x*blockDim.x + threadIdx.x;
  if(e >= NE) return;
  int r = row[e], c = col[e];

  float xr[HD], xc[HD], eb[EIN];
  #pragma unroll
  for(int k = 0; k < HD; k++) xr[k] = x[(size_t)r*HD + k];
  #pragma unroll
  for(int k = 0; k < HD; k++) xc[k] = x[(size_t)c*HD + k];
  #pragma unroll
  for(int k = 0; k < EIN; k++) eb[k] = eraw[(size_t)e*EIN + k];

  // u = leaky(xr@emW1[0:32] + xc@emW1[32:64] + e_raw@emW1f + emb1f)
  float u[HD];
  #pragma unroll
  for(int o = 0; o < HD; o++) u[o] = emb1f[o];
  #pragma unroll
  for(int k = 0; k < HD; k++){ float v = xr[k]; const float* wp = emW1 + k*HD;
    #pragma unroll
    for(int o = 0; o < HD; o++) u[o] += v * wp[o]; }
  #pragma unroll
  for(int k = 0; k < HD; k++){ float v = xc[k]; const float* wp = emW1 + (HD+k)*HD;
    #pragma unroll
    for(int o = 0; o < HD; o++) u[o] += v * wp[o]; }
  #pragma unroll
  for(int k = 0; k < EIN; k++){ float v = eb[k]; const float* wp = emW1f + k*HD;
    #pragma unroll
    for(int o = 0; o < HD; o++) u[o] += v * wp[o]; }
  #pragma unroll
  for(int o = 0; o < HD; o++) u[o] = lky(u[o]);

  float e2[HD];
  #pragma unroll
  for(int o = 0; o < HD; o++) e2[o] = emb2[o];
  #pragma unroll
  for(int k = 0; k < HD; k++){ float v = u[k]; const float* wp = emW2 + k*HD;
    #pragma unroll
    for(int o = 0; o < HD; o++) e2[o] += v * wp[o]; }

  float vv[HD];
  #pragma unroll
  for(int o = 0; o < HD; o++) vv[o] = nm1b1[o];
  #pragma unroll
  for(int k = 0; k < HD; k++){ float v = xr[k]; const float* wp = nm1W1 + k*HD;
    #pragma unroll
    for(int o = 0; o < HD; o++) vv[o] += v * wp[o]; }
  #pragma unroll
  for(int k = 0; k < HD; k++){ float v = e2[k]; const float* wp = nm1W1 + (HD+k)*HD;
    #pragma unroll
    for(int o = 0; o < HD; o++) vv[o] += v * wp[o]; }
  #pragma unroll
  for(int o = 0; o < HD; o++) vv[o] = lky(vv[o]);

  float* aggp = agg + (size_t)c * HD;
  #pragma unroll
  for(int o = 0; o < HD; o++){
    float h = nm1b2[o];
    #pragma unroll
    for(int k = 0; k < HD; k++) h += vv[k] * nm1W2[k*HD + o];
    atomicAdd(&aggp[o], h);
  }
  atomicAdd(&cnt[c], 1.f);
}

// ---------------------------------------------------------------- final node model + log_softmax
__global__ __launch_bounds__(256) void final_kernel(const float* __restrict__ x,
                                                    const float* __restrict__ agg,
                                                    const float* __restrict__ cnt,
                                                    const float* __restrict__ W1,
                                                    const float* __restrict__ b1,
                                                    const float* __restrict__ W2,
                                                    const float* __restrict__ b2,
                                                    float* __restrict__ out){
  int n = blockIdx.x*blockDim.x + threadIdx.x;
  if(n >= NN) return;
  float inv = 1.f / fmaxf(cnt[n], 1.f);
  const float* xp = x + (size_t)n * HD;
  const float* ap = agg + (size_t)n * HD;

  float t[HD];
  #pragma unroll
  for(int o = 0; o < HD; o++) t[o] = b1[o];
  #pragma unroll
  for(int k = 0; k < HD; k++){ float v = xp[k]; const float* wp = W1 + k*HD;
    #pragma unroll
    for(int o = 0; o < HD; o++) t[o] += v * wp[o]; }
  #pragma unroll
  for(int k = 0; k < HD; k++){ float v = ap[k] * inv; const float* wp = W1 + (HD+k)*HD;
    #pragma unroll
    for(int o = 0; o < HD; o++) t[o] += v * wp[o]; }

  float a0 = b2[0], a1 = b2[1];
  #pragma unroll
  for(int k = 0; k < HD; k++){ float v = lky(t[k]); a0 += v * W2[k*2]; a1 += v * W2[k*2+1]; }

  float m  = fmaxf(a0, a1);
  float ls = m + logf(expf(a0 - m) + expf(a1 - m));
  out[(size_t)n*2]   = a0 - ls;
  out[(size_t)n*2+1] = a1 - ls;
}

// ---------------------------------------------------------------- launch
extern "C" void kernel_launch(void* const* d_in, const int* in_sizes, int n_in,
                              void* d_out, int out_size, void* d_ws, size_t ws_size,
                              hipStream_t stream){
  const float* x  = (const float*)d_in[0];
  const int*   ei = (const int*)  d_in[1];
  const float* e  = (const float*)d_in[2];
  const float* bn_node_g = (const float*)d_in[4];
  const float* bn_node_b = (const float*)d_in[5];
  const float* bn_edge_g = (const float*)d_in[6];
  const float* bn_edge_b = (const float*)d_in[7];
  const float* lW1[3], *lb1[3], *lW2[3], *lb2[3], *lroot[3], *lbias[3];
  for(int l = 0; l < 3; l++){
    lW1[l]   = (const float*)d_in[8 + 6*l + 0];
    lb1[l]   = (const float*)d_in[8 + 6*l + 1];
    lW2[l]   = (const float*)d_in[8 + 6*l + 2];
    lb2[l]   = (const float*)d_in[8 + 6*l + 3];
    lroot[l] = (const float*)d_in[8 + 6*l + 4];
    lbias[l] = (const float*)d_in[8 + 6*l + 5];
  }
  const float* emW1  = (const float*)d_in[26];
  const float* emb1  = (const float*)d_in[27];
  const float* emW2  = (const float*)d_in[28];
  const float* emb2  = (const float*)d_in[29];
  const float* nm1W1 = (const float*)d_in[30];
  const float* nm1b1 = (const float*)d_in[31];
  const float* nm1W2 = (const float*)d_in[32];
  const float* nm1b2 = (const float*)d_in[33];
  const float* nm2W1 = (const float*)d_in[34];
  const float* nm2b1 = (const float*)d_in[35];
  const float* nm2W2 = (const float*)d_in[36];
  const float* nm2b2 = (const float*)d_in[37];

  const int* rowp = ei;
  const int* colp = ei + NE;

  // workspace layout (floats)
  float* ws    = (float*)d_ws;
  float* x_bn  = ws;                               // NN*16
  float* x_a   = x_bn + (size_t)NN*NIN;            // NN*32
  float* x_b   = x_a  + (size_t)NN*HD;             // NN*32
  float* T1    = x_b  + (size_t)NN*HD;             // NE*32
  float* scr   = T1   + (size_t)NE*HD;             // 8192 scratch
  float* sums_e = scr;          // 38 used
  float* sums_x = scr + 64;     // 32 used
  float* ss     = scr + 128;    // 70 used
  float* W1f    = scr + 256;    // 3*640
  float* b1f    = scr + 2304;   // 3*32
  float* emW1f  = scr + 2432;   // 608
  float* emb1f  = scr + 3072;   // 32
  // agg/cnt alias T1 (T1 dead after layer-2 msg)
  float* agg = T1;                // NN*32
  float* cnt = T1 + (size_t)NN*HD; // NN

  zero_kernel<<<1, 256, 0, stream>>>(scr, 256);
  stats_kernel<EIN><<<256, 256, 0, stream>>>(e, NE, sums_e);
  stats_kernel<NIN><<<256, 256, 0, stream>>>(x, NN, sums_x);
  finalize_stats<<<1, 64, 0, stream>>>(sums_e, sums_x, bn_edge_g, bn_edge_b,
                                       bn_node_g, bn_node_b, ss);
  fold_kernel<<<1, 128, 0, stream>>>(ss, lW1[0], lb1[0], lW1[1], lb1[1], lW1[2], lb1[2],
                                     emW1, emb1, W1f, b1f, emW1f, emb1f);
  normalize_kernel<NIN><<<1024, 256, 0, stream>>>(x, x_bn, ss + 2*EIN, NN);

  constexpr int EPB = 128;
  const int mblocks = (NE + EPB - 1) / EPB;
  const int nblocks = (NN*HD + 255) / 256;

  // layer 0 (din=16): x_bn -> x_a
  root_kernel<NIN><<<nblocks, 256, 0, stream>>>(x_bn, lroot[0], lbias[0], x_a);
  t1_kernel<NIN><<<(NE*NIN + 255)/256, 256, 0, stream>>>(e, W1f + 0*640, b1f + 0*32, T1);
  msg2_kernel<NIN, 4, EPB><<<mblocks, 256, 0, stream>>>(T1, rowp, colp, x_bn,
                                                        lW2[0], lb2[0], x_a);
  // layer 1 (din=32): x_a -> x_b
  root_kernel<HD><<<nblocks, 256, 0, stream>>>(x_a, lroot[1], lbias[1], x_b);
  t1_kernel<HD><<<(NE*HD + 255)/256, 256, 0, stream>>>(e, W1f + 1*640, b1f + 1*32, T1);
  msg2_kernel<HD, 8, EPB><<<mblocks, 256, 0, stream>>>(T1, rowp, colp, x_a,
                                                       lW2[1], lb2[1], x_b);
  // layer 2 (din=32): x_b -> x_a
  root_kernel<HD><<<nblocks, 256, 0, stream>>>(x_b, lroot[2], lbias[2], x_a);
  t1_kernel<HD><<<(NE*HD + 255)/256, 256, 0, stream>>>(e, W1f + 2*640, b1f + 2*32, T1);
  msg2_kernel<HD, 8, EPB><<<mblocks, 256, 0, stream>>>(T1, rowp, colp, x_b,
                                                       lW2[2], lb2[2], x_a);

  // predictor (agg/cnt alias T1 region — zero first)
  zero_kernel<<<2048, 256, 0, stream>>>(agg, NN*HD + NN);
  pred_edge_kernel<<<(NE + 255)/256, 256, 0, stream>>>(x_a, e, rowp, colp,
                                                       emW1, emW1f, emb1f, emW2, emb2,
                                                       nm1W1, nm1b1, nm1W2, nm1b2,
                                                       agg, cnt);
  final_kernel<<<(NN + 255)/256, 256, 0, stream>>>(x_a, agg, cnt,
                                                   nm2W1, nm2b1, nm2W2, nm2b2,
                                                   (float*)d_out);
}

// Round 3
// 742.172 us; speedup vs baseline: 2.6549x; 1.5622x over previous
//
#include <hip/hip_runtime.h>
#include <math.h>

constexpr int NN  = 50000;   // nodes
constexpr int NE  = 150000;  // edges
constexpr int NIN = 16;      // node features in
constexpr int EIN = 19;      // edge features in
constexpr int HD  = 32;      // hidden H
constexpr int NTILES = NE / 16;  // 9375 exactly

#define LEAK  0.1f
#define BNEPS 1e-5f

typedef __attribute__((ext_vector_type(8))) short bfrag;    // 8 bf16 = 4 VGPR
typedef __attribute__((ext_vector_type(4))) float f32x4;
typedef __attribute__((ext_vector_type(4))) int   i32x4;

__device__ __forceinline__ float lky(float v){ return fmaxf(v, LEAK*v); }
__device__ __forceinline__ unsigned short f2bf(float f){
  unsigned u = __float_as_uint(f);
  return (unsigned short)((u + 0x7FFFu + ((u >> 16) & 1u)) >> 16);   // RNE
}

// ---------------------------------------------------------------- zero
__global__ void zero_kernel(float* __restrict__ p, int n){
  int stride = gridDim.x * blockDim.x;
  for(int i = blockIdx.x*blockDim.x + threadIdx.x; i < n; i += stride) p[i] = 0.f;
}

// ---------------------------------------------------------------- BN stats
template<int C>
__global__ void stats_kernel(const float* __restrict__ data, int rows, float* __restrict__ sums){
  __shared__ float ls[2*C];
  for(int i = threadIdx.x; i < 2*C; i += blockDim.x) ls[i] = 0.f;
  __syncthreads();
  float s[C], q[C];
  #pragma unroll
  for(int c = 0; c < C; c++){ s[c] = 0.f; q[c] = 0.f; }
  int stride = gridDim.x * blockDim.x;
  for(int r = blockIdx.x*blockDim.x + threadIdx.x; r < rows; r += stride){
    const float* rp = data + (size_t)r * C;
    #pragma unroll
    for(int c = 0; c < C; c++){ float v = rp[c]; s[c] += v; q[c] += v*v; }
  }
  #pragma unroll
  for(int c = 0; c < C; c++){ atomicAdd(&ls[c], s[c]); atomicAdd(&ls[C+c], q[c]); }
  __syncthreads();
  for(int i = threadIdx.x; i < 2*C; i += blockDim.x) atomicAdd(&sums[i], ls[i]);
}

// ss layout: scale_e[19], shift_e[19], scale_x[16], shift_x[16]
__global__ void finalize_stats(const float* __restrict__ sums_e, const float* __restrict__ sums_x,
                               const float* __restrict__ ge, const float* __restrict__ be,
                               const float* __restrict__ gx, const float* __restrict__ bx,
                               float* __restrict__ ss){
  int t = threadIdx.x;
  if(t < EIN){
    float m = sums_e[t] / (float)NE;
    float v = sums_e[EIN+t] / (float)NE - m*m;
    float sc = ge[t] * rsqrtf(v + BNEPS);
    ss[t] = sc; ss[EIN+t] = be[t] - m*sc;
  } else if(t < EIN + NIN){
    int c = t - EIN;
    float m = sums_x[c] / (float)NN;
    float v = sums_x[NIN+c] / (float)NN - m*m;
    float sc = gx[c] * rsqrtf(v + BNEPS);
    ss[2*EIN + c] = sc; ss[2*EIN + NIN + c] = bx[c] - m*sc;
  }
}

// ---------------------------------------------------------------- fold BN(e) into W1/b1 + predictor
__global__ void fold_kernel(const float* __restrict__ ss,
                            const float* __restrict__ l0W1, const float* __restrict__ l0b1,
                            const float* __restrict__ l1W1, const float* __restrict__ l1b1,
                            const float* __restrict__ l2W1, const float* __restrict__ l2b1,
                            const float* __restrict__ emW1, const float* __restrict__ emb1,
                            float* __restrict__ W1f, float* __restrict__ b1f,
                            float* __restrict__ emW1f, float* __restrict__ emb1f){
  int t = threadIdx.x;
  int seg = t >> 5, j = t & 31;
  if(seg == 0){
    if(j < NIN){
      float acc = l0b1[j];
      for(int k = 0; k < EIN; k++){
        W1f[0*640 + k*NIN + j] = ss[k] * l0W1[k*NIN + j];
        acc += ss[EIN+k] * l0W1[k*NIN + j];
      }
      b1f[0*32 + j] = acc;
    }
  } else if(seg == 1){
    float acc = l1b1[j];
    for(int k = 0; k < EIN; k++){
      W1f[1*640 + k*HD + j] = ss[k] * l1W1[k*HD + j];
      acc += ss[EIN+k] * l1W1[k*HD + j];
    }
    b1f[1*32 + j] = acc;
  } else if(seg == 2){
    float acc = l2b1[j];
    for(int k = 0; k < EIN; k++){
      W1f[2*640 + k*HD + j] = ss[k] * l2W1[k*HD + j];
      acc += ss[EIN+k] * l2W1[k*HD + j];
    }
    b1f[2*32 + j] = acc;
  } else if(seg == 3){
    float acc = emb1[j];
    for(int k = 0; k < EIN; k++){
      emW1f[k*HD + j] = ss[k] * emW1[(2*HD+k)*HD + j];
      acc += ss[EIN+k] * emW1[(2*HD+k)*HD + j];
    }
    emb1f[j] = acc;
  }
}

template<int C>
__global__ void normalize_kernel(const float* __restrict__ in, float* __restrict__ outp,
                                 const float* __restrict__ ss, int rows){
  int n = rows * C;
  int stride = gridDim.x * blockDim.x;
  for(int i = blockIdx.x*blockDim.x + threadIdx.x; i < n; i += stride){
    int c = i % C;
    outp[i] = in[i] * ss[c] + ss[C + c];
  }
}

// ---------------------------------------------------------------- pack W2 into B-fragment layout (bf16)
// pack[c*512 + l*8 + j] = W2[k][c*16 + (l&15)] with k = 8*(l>>4)+j  (0 if k>=DIN)
template<int DIN, int NCH>
__global__ void w2pack_kernel(const float* __restrict__ W2, short* __restrict__ outp){
  int idx = blockIdx.x*blockDim.x + threadIdx.x;
  if(idx >= NCH*512) return;
  int c = idx >> 9, l = (idx >> 3) & 63, j = idx & 7;
  int k = 8*(l>>4) + j;
  int n = c*16 + (l & 15);
  float v = (k < DIN) ? W2[(size_t)k*(DIN*HD) + n] : 0.f;
  outp[idx] = (short)f2bf(v);
}

// ---------------------------------------------------------------- T1 = leaky(e_raw @ W1f + b1f) -> bf16 [E,32] (zero-padded)
template<int DIN>
__global__ __launch_bounds__(256) void t1_kernel(const float* __restrict__ eraw,
                                                 const float* __restrict__ W1f,
                                                 const float* __restrict__ b1f,
                                                 short* __restrict__ T1){
  int idx = blockIdx.x*blockDim.x + threadIdx.x;
  if(idx >= NE*16) return;
  int e = idx >> 4, j0 = idx & 15;
  const float* ep = eraw + (size_t)e*EIN;
  float eb[EIN];
  #pragma unroll
  for(int k = 0; k < EIN; k++) eb[k] = ep[k];

  float a = b1f[j0];
  #pragma unroll
  for(int k = 0; k < EIN; k++) a = fmaf(eb[k], W1f[k*DIN + j0], a);
  short r0 = (short)f2bf(lky(a));
  short r1 = 0;
  if(DIN == 32){
    float b = b1f[j0 + 16];
    #pragma unroll
    for(int k = 0; k < EIN; k++) b = fmaf(eb[k], W1f[k*DIN + j0 + 16], b);
    r1 = (short)f2bf(lky(b));
  }
  T1[(size_t)e*32 + j0]      = r0;
  T1[(size_t)e*32 + j0 + 16] = r1;
}

// ---------------------------------------------------------------- x_next = x @ root + bias
template<int DIN>
__global__ __launch_bounds__(256) void root_kernel(const float* __restrict__ xin,
                                                   const float* __restrict__ root,
                                                   const float* __restrict__ bias,
                                                   float* __restrict__ xout){
  int idx = blockIdx.x*blockDim.x + threadIdx.x;
  if(idx >= NN * HD) return;
  int node = idx / HD, o = idx % HD;
  const float* xr = xin + (size_t)node * DIN;
  float acc = bias[o];
  #pragma unroll
  for(int k = 0; k < DIN; k++) acc += xr[k] * root[k*HD + o];
  xout[idx] = acc;
}

// ---------------------------------------------------------------- MFMA msg: 16-edge tile per wave, 4 waves/block
// U[e][n] = (T1@W2)[e][n] + b2[n]; msg[e][o] = sum_i x[row[e]][i]*leaky(U[e][i*32+o])
template<int DIN, int NCH>
__global__ __launch_bounds__(256) void msg3_kernel(const short* __restrict__ T1,
                                                   const int* __restrict__ rowp,
                                                   const int* __restrict__ colp,
                                                   const float* __restrict__ xin,
                                                   const short* __restrict__ w2p,
                                                   const float* __restrict__ b2,
                                                   float* __restrict__ xout){
  constexpr int XGP = DIN + 4;   // padded LDS row (16B multiple, bank-spread)
  __shared__ short w2s[NCH*512];
  __shared__ float b2s[NCH*16];
  __shared__ float xgs[4][16][XGP];

  const int tid  = threadIdx.x;
  const int l    = tid & 63;
  const int wid  = tid >> 6;
  const int grp  = l >> 4, lo16 = l & 15;

  // stage packed W2 (+ b2) into LDS, linear
  for(int t = tid; t < NCH*64; t += 256)
    ((i32x4*)w2s)[t] = ((const i32x4*)w2p)[t];
  for(int t = tid; t < NCH*16; t += 256) b2s[t] = b2[t];
  __syncthreads();

  int tile = blockIdx.x*4 + wid;
  if(tile >= NTILES) return;
  int e0 = tile * 16;

  // stage x[row[e]] tile (fp32) into per-wave LDS
  {
    int r = rowp[e0 + lo16];
    if(DIN == 32){
      const f32x4* xp = (const f32x4*)(xin + (size_t)r*32 + grp*8);
      *(f32x4*)&xgs[wid][lo16][grp*8]     = xp[0];
      *(f32x4*)&xgs[wid][lo16][grp*8 + 4] = xp[1];
    } else {
      const f32x4* xp = (const f32x4*)(xin + (size_t)r*16 + grp*4);
      *(f32x4*)&xgs[wid][lo16][grp*4] = xp[0];
    }
  }

  // A fragment: T1[e0+lo16][8*grp .. +8] bf16
  bfrag af = *(const bfrag*)(T1 + (size_t)(e0 + lo16)*32 + grp*8);

  f32x4 m0; m0[0]=0.f; m0[1]=0.f; m0[2]=0.f; m0[3]=0.f;
  f32x4 m1 = m0;
  const f32x4 z = m0;

  #pragma unroll 4
  for(int i = 0; i < NCH/2; i++){
    bfrag b0 = *(const bfrag*)&w2s[((2*i  )*64 + l)*8];
    bfrag b1 = *(const bfrag*)&w2s[((2*i+1)*64 + l)*8];
    f32x4 u0 = __builtin_amdgcn_mfma_f32_16x16x32_bf16(af, b0, z, 0, 0, 0);
    f32x4 u1 = __builtin_amdgcn_mfma_f32_16x16x32_bf16(af, b1, z, 0, 0, 0);
    float bv0 = b2s[(2*i)*16 + lo16];
    float bv1 = b2s[(2*i+1)*16 + lo16];
    #pragma unroll
    for(int reg = 0; reg < 4; reg++){
      float xv = xgs[wid][grp*4 + reg][i];
      float a0 = u0[reg] + bv0; a0 = fmaxf(a0, LEAK*a0);
      float a1 = u1[reg] + bv1; a1 = fmaxf(a1, LEAK*a1);
      m0[reg] = fmaf(xv, a0, m0[reg]);
      m1[reg] = fmaf(xv, a1, m1[reg]);
    }
  }

  // scatter: C layout col=lo16, rows = grp*4+reg
  #pragma unroll
  for(int reg = 0; reg < 4; reg++){
    int ce = colp[e0 + grp*4 + reg];
    atomicAdd(&xout[(size_t)ce*HD + lo16],      m0[reg]);
    atomicAdd(&xout[(size_t)ce*HD + 16 + lo16], m1[reg]);
  }
}

// ---------------------------------------------------------------- fused MetaLayer edge model (vectorized gathers)
__global__ __launch_bounds__(256) void pred_edge_kernel(const float* __restrict__ x,
                                                        const float* __restrict__ eraw,
                                                        const int* __restrict__ row,
                                                        const int* __restrict__ col,
                                                        const float* __restrict__ emW1,
                                                        const float* __restrict__ emW1f,
                                                        const float* __restrict__ emb1f,
                                                        const float* __restrict__ emW2,
                                                        const float* __restrict__ emb2,
                                                        const float* __restrict__ nm1W1,
                                                        const float* __restrict__ nm1b1,
                                                        const float* __restrict__ nm1W2,
                                                        const float* __restrict__ nm1b2,
                                                        float* __restrict__ agg,
                                                        float* __restrict__ cnt){
  int e = blockIdx.x*blockDim.x + threadIdx.x;
  if(e >= NE) return;
  int r = row[e], c = col[e];

  // issue all gathers as float4 (8+8 dwordx4 in flight)
  f32x4 xr4[8], xc4[8];
  const f32x4* xrp = (const f32x4*)(x + (size_t)r*HD);
  const f32x4* xcp = (const f32x4*)(x + (size_t)c*HD);
  #pragma unroll
  for(int k = 0; k < 8; k++) xr4[k] = xrp[k];
  #pragma unroll
  for(int k = 0; k < 8; k++) xc4[k] = xcp[k];
  float eb[EIN];
  #pragma unroll
  for(int k = 0; k < EIN; k++) eb[k] = eraw[(size_t)e*EIN + k];

  float u[HD];
  #pragma unroll
  for(int o = 0; o < HD; o++) u[o] = emb1f[o];
  #pragma unroll
  for(int k = 0; k < HD; k++){ float v = xr4[k>>2][k&3]; const float* wp = emW1 + k*HD;
    #pragma unroll
    for(int o = 0; o < HD; o++) u[o] += v * wp[o]; }
  #pragma unroll
  for(int k = 0; k < HD; k++){ float v = xc4[k>>2][k&3]; const float* wp = emW1 + (HD+k)*HD;
    #pragma unroll
    for(int o = 0; o < HD; o++) u[o] += v * wp[o]; }
  #pragma unroll
  for(int k = 0; k < EIN; k++){ float v = eb[k]; const float* wp = emW1f + k*HD;
    #pragma unroll
    for(int o = 0; o < HD; o++) u[o] += v * wp[o]; }
  #pragma unroll
  for(int o = 0; o < HD; o++) u[o] = lky(u[o]);

  float e2[HD];
  #pragma unroll
  for(int o = 0; o < HD; o++) e2[o] = emb2[o];
  #pragma unroll
  for(int k = 0; k < HD; k++){ float v = u[k]; const float* wp = emW2 + k*HD;
    #pragma unroll
    for(int o = 0; o < HD; o++) e2[o] += v * wp[o]; }

  float vv[HD];
  #pragma unroll
  for(int o = 0; o < HD; o++) vv[o] = nm1b1[o];
  #pragma unroll
  for(int k = 0; k < HD; k++){ float v = xr4[k>>2][k&3]; const float* wp = nm1W1 + k*HD;
    #pragma unroll
    for(int o = 0; o < HD; o++) vv[o] += v * wp[o]; }
  #pragma unroll
  for(int k = 0; k < HD; k++){ float v = e2[k]; const float* wp = nm1W1 + (HD+k)*HD;
    #pragma unroll
    for(int o = 0; o < HD; o++) vv[o] += v * wp[o]; }
  #pragma unroll
  for(int o = 0; o < HD; o++) vv[o] = lky(vv[o]);

  float* aggp = agg + (size_t)c * HD;
  #pragma unroll
  for(int o = 0; o < HD; o++){
    float h = nm1b2[o];
    #pragma unroll
    for(int k = 0; k < HD; k++) h += vv[k] * nm1W2[k*HD + o];
    atomicAdd(&aggp[o], h);
  }
  atomicAdd(&cnt[c], 1.f);
}

// ---------------------------------------------------------------- final node model + log_softmax
__global__ __launch_bounds__(256) void final_kernel(const float* __restrict__ x,
                                                    const float* __restrict__ agg,
                                                    const float* __restrict__ cnt,
                                                    const float* __restrict__ W1,
                                                    const float* __restrict__ b1,
                                                    const float* __restrict__ W2,
                                                    const float* __restrict__ b2,
                                                    float* __restrict__ out){
  int n = blockIdx.x*blockDim.x + threadIdx.x;
  if(n >= NN) return;
  float inv = 1.f / fmaxf(cnt[n], 1.f);
  const float* xp = x + (size_t)n * HD;
  const float* ap = agg + (size_t)n * HD;

  float t[HD];
  #pragma unroll
  for(int o = 0; o < HD; o++) t[o] = b1[o];
  #pragma unroll
  for(int k = 0; k < HD; k++){ float v = xp[k]; const float* wp = W1 + k*HD;
    #pragma unroll
    for(int o = 0; o < HD; o++) t[o] += v * wp[o]; }
  #pragma unroll
  for(int k = 0; k < HD; k++){ float v = ap[k] * inv; const float* wp = W1 + (HD+k)*HD;
    #pragma unroll
    for(int o = 0; o < HD; o++) t[o] += v * wp[o]; }

  float a0 = b2[0], a1 = b2[1];
  #pragma unroll
  for(int k = 0; k < HD; k++){ float v = lky(t[k]); a0 += v * W2[k*2]; a1 += v * W2[k*2+1]; }

  float m  = fmaxf(a0, a1);
  float ls = m + logf(expf(a0 - m) + expf(a1 - m));
  out[(size_t)n*2]   = a0 - ls;
  out[(size_t)n*2+1] = a1 - ls;
}

// ---------------------------------------------------------------- launch
extern "C" void kernel_launch(void* const* d_in, const int* in_sizes, int n_in,
                              void* d_out, int out_size, void* d_ws, size_t ws_size,
                              hipStream_t stream){
  const float* x  = (const float*)d_in[0];
  const int*   ei = (const int*)  d_in[1];
  const float* e  = (const float*)d_in[2];
  const float* bn_node_g = (const float*)d_in[4];
  const float* bn_node_b = (const float*)d_in[5];
  const float* bn_edge_g = (const float*)d_in[6];
  const float* bn_edge_b = (const float*)d_in[7];
  const float* lW1[3], *lb1[3], *lW2[3], *lb2[3], *lroot[3], *lbias[3];
  for(int l = 0; l < 3; l++){
    lW1[l]   = (const float*)d_in[8 + 6*l + 0];
    lb1[l]   = (const float*)d_in[8 + 6*l + 1];
    lW2[l]   = (const float*)d_in[8 + 6*l + 2];
    lb2[l]   = (const float*)d_in[8 + 6*l + 3];
    lroot[l] = (const float*)d_in[8 + 6*l + 4];
    lbias[l] = (const float*)d_in[8 + 6*l + 5];
  }
  const float* emW1  = (const float*)d_in[26];
  const float* emb1  = (const float*)d_in[27];
  const float* emW2  = (const float*)d_in[28];
  const float* emb2  = (const float*)d_in[29];
  const float* nm1W1 = (const float*)d_in[30];
  const float* nm1b1 = (const float*)d_in[31];
  const float* nm1W2 = (const float*)d_in[32];
  const float* nm1b2 = (const float*)d_in[33];
  const float* nm2W1 = (const float*)d_in[34];
  const float* nm2b1 = (const float*)d_in[35];
  const float* nm2W2 = (const float*)d_in[36];
  const float* nm2b2 = (const float*)d_in[37];

  const int* rowp = ei;
  const int* colp = ei + NE;

  // workspace layout (float units)
  float* ws   = (float*)d_ws;
  float* x_bn = ws;                                 // 800000
  float* x_a  = x_bn + (size_t)NN*NIN;              // 1600000
  float* x_b  = x_a  + (size_t)NN*HD;               // 1600000
  float* scr  = x_b  + (size_t)NN*HD;               // 4096
  float* sums_e = scr;          // 38
  float* sums_x = scr + 64;     // 32
  float* ss     = scr + 128;    // 70
  float* W1f    = scr + 256;    // 3*640
  float* b1f    = scr + 2304;   // 3*32
  float* emW1f  = scr + 2432;   // 608
  float* emb1f  = scr + 3072;   // 32
  short* w2pk   = (short*)(scr + 4096);             // 3 * 32768 shorts (64KB each)
  short* T1     = w2pk + 3*32768;                   // NE*32 bf16
  float* agg    = (float*)T1;                       // alias (T1 dead after layer-2 msg)
  float* cnt    = agg + (size_t)NN*HD;

  zero_kernel<<<1, 256, 0, stream>>>(scr, 256);
  stats_kernel<EIN><<<256, 256, 0, stream>>>(e, NE, sums_e);
  stats_kernel<NIN><<<256, 256, 0, stream>>>(x, NN, sums_x);
  finalize_stats<<<1, 64, 0, stream>>>(sums_e, sums_x, bn_edge_g, bn_edge_b,
                                       bn_node_g, bn_node_b, ss);
  fold_kernel<<<1, 128, 0, stream>>>(ss, lW1[0], lb1[0], lW1[1], lb1[1], lW1[2], lb1[2],
                                     emW1, emb1, W1f, b1f, emW1f, emb1f);
  normalize_kernel<NIN><<<1024, 256, 0, stream>>>(x, x_bn, ss + 2*EIN, NN);

  // pack W2 -> bf16 B-fragment layout (once)
  w2pack_kernel<NIN, 32><<<(32*512 + 255)/256, 256, 0, stream>>>(lW2[0], w2pk + 0*32768);
  w2pack_kernel<HD,  64><<<(64*512 + 255)/256, 256, 0, stream>>>(lW2[1], w2pk + 1*32768);
  w2pack_kernel<HD,  64><<<(64*512 + 255)/256, 256, 0, stream>>>(lW2[2], w2pk + 2*32768);

  const int t1blocks = (NE*16 + 255)/256;
  const int nblocks  = (NN*HD + 255)/256;
  const int mblocks  = (NTILES + 3)/4;

  // layer 0 (din=16): x_bn -> x_a
  root_kernel<NIN><<<nblocks, 256, 0, stream>>>(x_bn, lroot[0], lbias[0], x_a);
  t1_kernel<NIN><<<t1blocks, 256, 0, stream>>>(e, W1f + 0*640, b1f + 0*32, T1);
  msg3_kernel<NIN, 32><<<mblocks, 256, 0, stream>>>(T1, rowp, colp, x_bn,
                                                    w2pk + 0*32768, lb2[0], x_a);
  // layer 1 (din=32): x_a -> x_b
  root_kernel<HD><<<nblocks, 256, 0, stream>>>(x_a, lroot[1], lbias[1], x_b);
  t1_kernel<HD><<<t1blocks, 256, 0, stream>>>(e, W1f + 1*640, b1f + 1*32, T1);
  msg3_kernel<HD, 64><<<mblocks, 256, 0, stream>>>(T1, rowp, colp, x_a,
                                                   w2pk + 1*32768, lb2[1], x_b);
  // layer 2 (din=32): x_b -> x_a
  root_kernel<HD><<<nblocks, 256, 0, stream>>>(x_b, lroot[2], lbias[2], x_a);
  t1_kernel<HD><<<t1blocks, 256, 0, stream>>>(e, W1f + 2*640, b1f + 2*32, T1);
  msg3_kernel<HD, 64><<<mblocks, 256, 0, stream>>>(T1, rowp, colp, x_b,
                                                   w2pk + 2*32768, lb2[2], x_a);

  // predictor (agg/cnt alias T1 region — zero first)
  zero_kernel<<<2048, 256, 0, stream>>>(agg, NN*HD + NN);
  pred_edge_kernel<<<(NE + 255)/256, 256, 0, stream>>>(x_a, e, rowp, colp,
                                                       emW1, emW1f, emb1f, emW2, emb2,
                                                       nm1W1, nm1b1, nm1W2, nm1b2,
                                                       agg, cnt);
  final_kernel<<<(NN + 255)/256, 256, 0, stream>>>(x_a, agg, cnt,
                                                   nm2W1, nm2b1, nm2W2, nm2b2,
                                                   (float*)d_out);
}